// Round 7
// baseline (249.054 us; speedup 1.0000x reference)
//
#include <hip/hip_runtime.h>
#include <hip/hip_fp16.h>

namespace {

constexpr int B = 8, C = 64, H = 256, W = 256;
constexpr int HW = H * W;
constexpr int R1 = 72;        // K1 LDS row stride in halfs (144B = 9*16: b64/b128 aligned)
constexpr int TS = 68;        // K2 LDS tile row stride (floats)

typedef float v4f __attribute__((ext_vector_type(4)));
typedef unsigned int v4u __attribute__((ext_vector_type(4)));

union H4 { struct { __half2 lo, hi; } h; uint2 u; };

// ---------- K1: x_enc [b,c,hw] f32 -> ws [b,hw,c] f16 ----------
// tile: 256 hw x 64 c per block; 2048 blocks. Every global instr moves
// 1 KB CONTIGUOUS within one plane (DRAM-page friendly).
__global__ __launch_bounds__(256) void transpose_kernel(
    const float* __restrict__ x, __half* __restrict__ ws)
{
    __shared__ __align__(16) __half lt[256 * R1];   // 36 KB -> 4 blocks/CU
    const int t  = threadIdx.x;
    const int wv = t >> 6, l = t & 63;
    const int bid = blockIdx.x;           // B * (HW/256) = 2048
    const int b   = bid >> 8;
    const int hw0 = (bid & 255) << 8;

    const int sw = 8 * (l & 7);           // XOR column swizzle for this lane's rows

    #pragma unroll
    for (int k = 0; k < 4; ++k) {
        const int c4 = wv * 16 + k * 4;   // 4 adjacent channels
        v4f vv[4];
        #pragma unroll
        for (int j = 0; j < 4; ++j) {     // one full-wave 1KB contiguous read per plane
            vv[j] = __builtin_nontemporal_load(
                (const v4f*)(x + (size_t)(b * C + c4 + j) * HW + hw0 + 4 * l));
        }
        const int col = c4 ^ sw;          // swizzled column (8B-aligned)
        #pragma unroll
        for (int q = 0; q < 4; ++q) {     // pack 4ch -> one b64 LDS write per hw
            H4 pk;
            pk.h.lo = __halves2half2(__float2half(vv[0][q]), __float2half(vv[1][q]));
            pk.h.hi = __halves2half2(__float2half(vv[2][q]), __float2half(vv[3][q]));
            *(uint2*)&lt[(4 * l + q) * R1 + col] = pk.u;
        }
    }
    __syncthreads();

    // store: 8 passes; each wave-instr writes 8 full 128B rows = 1KB contiguous
    #pragma unroll
    for (int p = 0; p < 8; ++p) {
        const int hw = p * 32 + (t >> 3);
        const int g  = t & 7;                       // channel group 8g..8g+7
        const int s  = (hw >> 2) & 7;               // de-swizzle
        const v4u r = *(const v4u*)&lt[hw * R1 + 8 * (g ^ s)];  // b128, 16B aligned
        *(v4u*)(ws + ((size_t)b * HW + hw0 + hw) * 64 + 8 * g) = r;
    }
}

// ---------- K2: weights + coalesced gather from ws + masked store ----------
__global__ __launch_bounds__(256) void warp_main(
    const float* __restrict__ phi,
    const __half* __restrict__ ws,
    const float* __restrict__ mm,
    float* __restrict__ out)
{
    __shared__ float tile[64 * TS];       // [c][p] — not zero-filled; mask handles zeros
    __shared__ float s_w[4][64];
    __shared__ int   s_o[4][64];
    __shared__ int   s_p[64];
    __shared__ int   s_n;
    __shared__ unsigned long long s_mask;

    const int t   = threadIdx.x;
    const int bid = blockIdx.x;           // 8192
    const int wt  = bid & 3;
    const int h   = (bid >> 2) & (H - 1);
    const int b   = bid >> 10;
    const int w0  = wt * 64;

    if (t < 64) {                         // wave 0 only
        const int lane = t;
        const int w    = w0 + lane;
        const int hw   = h * W + w;

        const float p0 = phi[(size_t)(b * 2 + 0) * HW + hw];
        const float p1 = phi[(size_t)(b * 2 + 1) * HW + hw];
        const float mv = mm[(size_t)b * HW + hw];

        const float gx = (2.0f * ((float)w + p0)) / (float)(W - 1) - 1.0f + 2.0f * p0;
        const float gy = (2.0f * ((float)h + p1)) / (float)(H - 1) - 1.0f + 2.0f * p1;
        const float ix = (gx + 1.0f) * (0.5f * (float)W) - 0.5f;
        const float iy = (gy + 1.0f) * (0.5f * (float)H) - 0.5f;

        const float x0f = floorf(ix);
        const float y0f = floorf(iy);
        const float fx1 = ix - x0f, fx0 = 1.0f - fx1;
        const float fy1 = iy - y0f, fy0 = 1.0f - fy1;

        const float wm1 = (float)(W - 1), hm1 = (float)(H - 1);
        const int x0 = (int)fminf(fmaxf(x0f,        0.0f), wm1);
        const int x1 = (int)fminf(fmaxf(x0f + 1.0f, 0.0f), wm1);
        const int y0 = (int)fminf(fmaxf(y0f,        0.0f), hm1);
        const int y1 = (int)fminf(fmaxf(y0f + 1.0f, 0.0f), hm1);

        const bool vx0 = (x0f >= 0.0f) && (x0f < (float)W);
        const bool vx1 = (x0f + 1.0f >= 0.0f) && (x0f + 1.0f < (float)W);
        const bool vy0 = (y0f >= 0.0f) && (y0f < (float)H);
        const bool vy1 = (y0f + 1.0f >= 0.0f) && (y0f + 1.0f < (float)H);

        const float w00 = fy0 * fx0 * ((vy0 && vx0) ? mv : 0.0f);
        const float w01 = fy0 * fx1 * ((vy0 && vx1) ? mv : 0.0f);
        const float w10 = fy1 * fx0 * ((vy1 && vx0) ? mv : 0.0f);
        const float w11 = fy1 * fx1 * ((vy1 && vx1) ? mv : 0.0f);

        const bool inb = (w00 + w01 + w10 + w11) != 0.0f;
        const unsigned long long mask = __ballot(inb);
        const int pos = __popcll(mask & ((1ULL << lane) - 1ULL));
        if (inb) {
            s_w[0][pos] = w00;  s_w[1][pos] = w01;
            s_w[2][pos] = w10;  s_w[3][pos] = w11;
            s_o[0][pos] = y0 * W + x0;
            s_o[1][pos] = y0 * W + x1;
            s_o[2][pos] = y1 * W + x0;
            s_o[3][pos] = y1 * W + x1;
            s_p[pos]    = lane;
        }
        if (lane == 0) { s_n = __popcll(mask); s_mask = mask; }
    }
    __syncthreads();

    // dense gathers: one wave per in-bounds pixel, lane = channel, 128B coalesced
    {
        const int wv   = t >> 6;
        const int lane = t & 63;
        const int n    = s_n;
        const __half* __restrict__ wsb = ws + (size_t)b * HW * 64 + lane;
        for (int i = wv; i < n; i += 4) {
            const float w00 = s_w[0][i], w01 = s_w[1][i];
            const float w10 = s_w[2][i], w11 = s_w[3][i];
            const float v = __half2float(wsb[(size_t)s_o[0][i] * 64]) * w00
                          + __half2float(wsb[(size_t)s_o[1][i] * 64]) * w01
                          + __half2float(wsb[(size_t)s_o[2][i] * 64]) * w10
                          + __half2float(wsb[(size_t)s_o[3][i] * 64]) * w11;
            tile[lane * TS + s_p[i]] = v;
        }
    }
    __syncthreads();

    // masked store: invalid pixels -> 0 via cndmask (no tile zero-fill needed)
    {
        const unsigned long long msk = s_mask;
        const size_t obase = (size_t)b * C * HW + (size_t)h * W + w0;
        const int cl = t >> 4;
        const int p4 = (t & 15) * 4;
        #pragma unroll
        for (int pass = 0; pass < 4; ++pass) {
            const int c = pass * 16 + cl;
            v4f v = *(const v4f*)&tile[c * TS + p4];
            v.x = ((msk >> (p4 + 0)) & 1ULL) ? v.x : 0.0f;
            v.y = ((msk >> (p4 + 1)) & 1ULL) ? v.y : 0.0f;
            v.z = ((msk >> (p4 + 2)) & 1ULL) ? v.z : 0.0f;
            v.w = ((msk >> (p4 + 3)) & 1ULL) ? v.w : 0.0f;
            __builtin_nontemporal_store(v, (v4f*)(out + obase + (size_t)c * HW + p4));
        }
    }
}

// ---------- fallback if ws too small ----------
__global__ __launch_bounds__(256) void warp_fallback(
    const float* __restrict__ phi,
    const float* __restrict__ xenc,
    const float* __restrict__ mm,
    float* __restrict__ out)
{
    const int tid = blockIdx.x * 256 + threadIdx.x;
    const int w = tid & (W - 1);
    const int h = (tid >> 8) & (H - 1);
    const int b = tid >> 16;
    const int hw = h * W + w;

    const float p0 = phi[(size_t)(b * 2 + 0) * HW + hw];
    const float p1 = phi[(size_t)(b * 2 + 1) * HW + hw];
    const float mv = mm[(size_t)b * HW + hw];

    const float gx = (2.0f * ((float)w + p0)) / (float)(W - 1) - 1.0f + 2.0f * p0;
    const float gy = (2.0f * ((float)h + p1)) / (float)(H - 1) - 1.0f + 2.0f * p1;
    const float ix = (gx + 1.0f) * (0.5f * (float)W) - 0.5f;
    const float iy = (gy + 1.0f) * (0.5f * (float)H) - 0.5f;

    const float x0f = floorf(ix);
    const float y0f = floorf(iy);
    const float fx1 = ix - x0f, fx0 = 1.0f - fx1;
    const float fy1 = iy - y0f, fy0 = 1.0f - fy1;

    const float wm1 = (float)(W - 1), hm1 = (float)(H - 1);
    const int x0 = (int)fminf(fmaxf(x0f,        0.0f), wm1);
    const int x1 = (int)fminf(fmaxf(x0f + 1.0f, 0.0f), wm1);
    const int y0 = (int)fminf(fmaxf(y0f,        0.0f), hm1);
    const int y1 = (int)fminf(fmaxf(y0f + 1.0f, 0.0f), hm1);

    const bool vx0 = (x0f >= 0.0f) && (x0f < (float)W);
    const bool vx1 = (x0f + 1.0f >= 0.0f) && (x0f + 1.0f < (float)W);
    const bool vy0 = (y0f >= 0.0f) && (y0f < (float)H);
    const bool vy1 = (y0f + 1.0f >= 0.0f) && (y0f + 1.0f < (float)H);

    const float w00 = fy0 * fx0 * ((vy0 && vx0) ? mv : 0.0f);
    const float w01 = fy0 * fx1 * ((vy0 && vx1) ? mv : 0.0f);
    const float w10 = fy1 * fx0 * ((vy1 && vx0) ? mv : 0.0f);
    const float w11 = fy1 * fx1 * ((vy1 && vx1) ? mv : 0.0f);
    const bool doGather = (w00 + w01 + w10 + w11) != 0.0f;

    const int o00 = y0 * W + x0, o01 = y0 * W + x1;
    const int o10 = y1 * W + x0, o11 = y1 * W + x1;

    const float* __restrict__ xb = xenc + (size_t)b * C * HW;
    float* __restrict__ ob = out + (size_t)b * C * HW + hw;

    #pragma unroll 4
    for (int c = 0; c < C; ++c) {
        float v = 0.0f;
        if (doGather) {
            const float* __restrict__ xc = xb + (size_t)c * HW;
            v = xc[o00] * w00 + xc[o01] * w01 + xc[o10] * w10 + xc[o11] * w11;
        }
        ob[(size_t)c * HW] = v;
    }
}

}  // namespace

extern "C" void kernel_launch(void* const* d_in, const int* in_sizes, int n_in,
                              void* d_out, int out_size, void* d_ws, size_t ws_size,
                              hipStream_t stream) {
    const float* phi  = (const float*)d_in[0];
    const float* xenc = (const float*)d_in[1];
    const float* mm   = (const float*)d_in[2];
    float* out = (float*)d_out;

    const size_t need = (size_t)B * HW * C * sizeof(__half);  // 64 MiB
    if (ws_size >= need) {
        __half* ws = (__half*)d_ws;
        transpose_kernel<<<dim3(B * (HW / 256)), dim3(256), 0, stream>>>(xenc, ws);
        warp_main<<<dim3(B * H * (W / 64)), dim3(256), 0, stream>>>(phi, ws, mm, out);
    } else {
        warp_fallback<<<dim3((B * HW) / 256), dim3(256), 0, stream>>>(phi, xenc, mm, out);
    }
}